// Round 1
// baseline (492.073 us; speedup 1.0000x reference)
//
#include <hip/hip_runtime.h>
#include <hip/hip_bf16.h>

#define NN 50000
#define EE 800000
#define FF 128
#define HH 128
#define HID2 64
#define TT 8
#define GG 64

// ---------------- K1: in-degree histogram (dst side, excludes self-loop) ----
__global__ void k_hist(const int* __restrict__ dst, int* __restrict__ deg) {
    int e = blockIdx.x * 256 + threadIdx.x;
    if (e < EE) atomicAdd(&deg[dst[e]], 1);
}

// ---------------- K2: single-block exclusive scan -> row_ptr, dinv, zero deg
__global__ __launch_bounds__(1024) void k_scan(int* __restrict__ deg,
                                               int* __restrict__ row_ptr,
                                               float* __restrict__ dinv) {
    const int C = 49;  // 1024*49 = 50176 >= NN
    __shared__ int sums[1024];
    int t = threadIdx.x;
    int base = t * C;
    int s = 0;
    for (int j = 0; j < C; j++) {
        int idx = base + j;
        if (idx < NN) s += deg[idx];
    }
    sums[t] = s;
    __syncthreads();
    // Hillis-Steele inclusive scan
    for (int off = 1; off < 1024; off <<= 1) {
        int v = sums[t];
        int w = (t >= off) ? sums[t - off] : 0;
        __syncthreads();
        sums[t] = v + w;
        __syncthreads();
    }
    int run = (t == 0) ? 0 : sums[t - 1];
    for (int j = 0; j < C; j++) {
        int idx = base + j;
        if (idx < NN) {
            int d = deg[idx];
            row_ptr[idx] = run;
            run += d;
            dinv[idx] = rsqrtf((float)(d + 1));  // +1 self-loop
            deg[idx] = 0;                        // reuse as fill cursor
        }
    }
    if (t == 1023) row_ptr[NN] = run;
}

// ---------------- K3: counting-sort fill of CSR col array ------------------
__global__ void k_fill(const int* __restrict__ src, const int* __restrict__ dst,
                       const int* __restrict__ row_ptr, int* __restrict__ cur,
                       int* __restrict__ srcs) {
    int e = blockIdx.x * 256 + threadIdx.x;
    if (e < EE) {
        int d = dst[e];
        int slot = row_ptr[d] + atomicAdd(&cur[d], 1);
        srcs[slot] = src[e];
    }
}

// ---------------- K4: h = x @ W  (fp32, LDS-tiled, 64x128 tile) ------------
__global__ __launch_bounds__(256) void k_gemm(const float* __restrict__ x,
                                              const float* __restrict__ W,
                                              float* __restrict__ h) {
    __shared__ float xs[64 * 36];   // 64 rows x 32 k, pad 36 (16B-aligned rows)
    __shared__ float ws[32 * 132];  // 32 k x 128 cols, pad 132
    int tid = threadIdx.x;
    int tx = tid & 15, ty = tid >> 4;
    int r0 = blockIdx.x * 64;
    float acc[4][8];
#pragma unroll
    for (int r = 0; r < 4; r++)
#pragma unroll
        for (int c = 0; c < 8; c++) acc[r][c] = 0.f;

    for (int k0 = 0; k0 < 128; k0 += 32) {
        {   // stage x tile: thread -> row=tid>>2, q=tid&3 (8 cols)
            int row = tid >> 2, q = tid & 3;
            int gr = r0 + row;
            float4 a0 = {0, 0, 0, 0}, a1 = {0, 0, 0, 0};
            if (gr < NN) {
                const float4* p = (const float4*)(x + (size_t)gr * 128 + k0 + q * 8);
                a0 = p[0]; a1 = p[1];
            }
            float* dp = &xs[row * 36 + q * 8];
            ((float4*)dp)[0] = a0; ((float4*)dp)[1] = a1;
        }
        {   // stage W tile: thread -> kr=tid>>3, q=tid&7 (16 cols)
            int kr = tid >> 3, q = tid & 7;
            const float4* p = (const float4*)(W + (size_t)(k0 + kr) * 128 + q * 16);
            float4 b0 = p[0], b1 = p[1], b2 = p[2], b3 = p[3];
            float* dp = &ws[kr * 132 + q * 16];
            ((float4*)dp)[0] = b0; ((float4*)dp)[1] = b1;
            ((float4*)dp)[2] = b2; ((float4*)dp)[3] = b3;
        }
        __syncthreads();
#pragma unroll
        for (int kk = 0; kk < 32; kk++) {
            float a[4];
#pragma unroll
            for (int r = 0; r < 4; r++) a[r] = xs[(ty * 4 + r) * 36 + kk];
            float4 b0 = *(const float4*)&ws[kk * 132 + tx * 8];
            float4 b1 = *(const float4*)&ws[kk * 132 + tx * 8 + 4];
            float bv[8] = {b0.x, b0.y, b0.z, b0.w, b1.x, b1.y, b1.z, b1.w};
#pragma unroll
            for (int r = 0; r < 4; r++)
#pragma unroll
                for (int c = 0; c < 8; c++)
                    acc[r][c] = fmaf(a[r], bv[c], acc[r][c]);
        }
        __syncthreads();
    }
#pragma unroll
    for (int r = 0; r < 4; r++) {
        int gr = r0 + ty * 4 + r;
        if (gr < NN) {
            float4 o0 = {acc[r][0], acc[r][1], acc[r][2], acc[r][3]};
            float4 o1 = {acc[r][4], acc[r][5], acc[r][6], acc[r][7]};
            float4* p = (float4*)(h + (size_t)gr * 128 + tx * 8);
            p[0] = o0; p[1] = o1;
        }
    }
}

// ---------------- K5: per-node gather aggregation + bias + relu ------------
__global__ __launch_bounds__(256) void k_aggr(const float* __restrict__ h,
                                              const int* __restrict__ row_ptr,
                                              const int* __restrict__ srcs,
                                              const float* __restrict__ dinv,
                                              const float* __restrict__ b,
                                              float* __restrict__ h2) {
    int wave = threadIdx.x >> 6;
    int lane = threadIdx.x & 63;
    int i = blockIdx.x * 4 + wave;  // grid sized so i < NN always
    float di = dinv[i];
    float2 v = ((const float2*)(h + (size_t)i * 128))[lane];
    float sw = di * di;  // self-loop weight
    float2 acc;
    acc.x = v.x * sw;
    acc.y = v.y * sw;
    int e0 = row_ptr[i], e1 = row_ptr[i + 1];
    for (int e = e0; e < e1; ++e) {
        int s = srcs[e];
        float w = dinv[s] * di;
        float2 hv = ((const float2*)(h + (size_t)s * 128))[lane];
        acc.x = fmaf(hv.x, w, acc.x);
        acc.y = fmaf(hv.y, w, acc.y);
    }
    float2 bb = ((const float2*)b)[lane];
    acc.x = fmaxf(acc.x + bb.x, 0.f);
    acc.y = fmaxf(acc.y + bb.y, 0.f);
    ((float2*)(h2 + (size_t)i * 128))[lane] = acc;
}

__device__ inline int lbound(const int* __restrict__ a, int n, int key) {
    int lo = 0, hi = n;
    while (lo < hi) {
        int mid = (lo + hi) >> 1;
        if (a[mid] < key) lo = mid + 1;
        else hi = mid;
    }
    return lo;
}

// ---------------- K6: group mean-pool partial sums -------------------------
__global__ __launch_bounds__(128) void k_pool(const float* __restrict__ h2,
                                              const int* __restrict__ batch,
                                              float* __restrict__ gsum) {
    int g = blockIdx.x >> 2, chunk = blockIdx.x & 3;
    int lo = lbound(batch, NN, g);
    int hi = lbound(batch, NN, g + 1);
    int cnt = hi - lo;
    int per = (cnt + 3) >> 2;
    int rs = lo + chunk * per;
    int re = rs + per;
    if (re > hi) re = hi;
    float s = 0.f;
    int f = threadIdx.x;
    for (int r = rs; r < re; ++r) s += h2[(size_t)r * 128 + f];
    atomicAdd(&gsum[g * 128 + f], s);
}

// ---------------- K7: head (fc1 + relu, actor softmax, critic) -------------
__global__ __launch_bounds__(64) void k_head(const float* __restrict__ gsum,
                                             const int* __restrict__ batch,
                                             const float* __restrict__ fc1_w,
                                             const float* __restrict__ fc1_b,
                                             const float* __restrict__ actor_w,
                                             const float* __restrict__ actor_b,
                                             const float* __restrict__ critic_w,
                                             const float* __restrict__ critic_b,
                                             float* __restrict__ out) {
    __shared__ float gs[128];
    __shared__ float zs[64];
    __shared__ float ls[8], es[8];
    int g = blockIdx.x, t = threadIdx.x;
    int lo = lbound(batch, NN, g), hi = lbound(batch, NN, g + 1);
    float invc = 1.f / fmaxf((float)(hi - lo), 1.f);
    gs[t] = gsum[g * 128 + t] * invc;
    gs[t + 64] = gsum[g * 128 + 64 + t] * invc;
    __syncthreads();
    float z = fc1_b[t];
    for (int k = 0; k < 128; k++) z = fmaf(gs[k], fc1_w[k * 64 + t], z);
    zs[t] = fmaxf(z, 0.f);
    __syncthreads();
    if (t < 8) {
        float l = actor_b[t];
        for (int k = 0; k < 64; k++) l = fmaf(zs[k], actor_w[k * 8 + t], l);
        ls[t] = l;
    }
    __syncthreads();
    if (t < 8) {
        float m = ls[0];
#pragma unroll
        for (int j = 1; j < 8; j++) m = fmaxf(m, ls[j]);
        es[t] = expf(ls[t] - m);
    }
    __syncthreads();
    if (t < 8) {
        float ssum = 0.f;
#pragma unroll
        for (int j = 0; j < 8; j++) ssum += es[j];
        out[g * 8 + t] = es[t] / ssum;
    }
    if (t == 32) {
        float v = critic_b[0];
        for (int k = 0; k < 64; k++) v = fmaf(zs[k], critic_w[k], v);
        out[GG * TT + g] = v;
    }
}

extern "C" void kernel_launch(void* const* d_in, const int* in_sizes, int n_in,
                              void* d_out, int out_size, void* d_ws, size_t ws_size,
                              hipStream_t stream) {
    const float* x        = (const float*)d_in[0];
    const int*   ei       = (const int*)d_in[1];
    const int*   batch    = (const int*)d_in[2];
    const float* W        = (const float*)d_in[3];
    const float* b        = (const float*)d_in[4];
    const float* fc1_w    = (const float*)d_in[5];
    const float* fc1_b    = (const float*)d_in[6];
    const float* actor_w  = (const float*)d_in[7];
    const float* actor_b  = (const float*)d_in[8];
    const float* critic_w = (const float*)d_in[9];
    const float* critic_b = (const float*)d_in[10];
    float* out = (float*)d_out;

    char* ws = (char*)d_ws;
    size_t off = 0;
    float* h       = (float*)(ws + off); off += (size_t)NN * HH * 4;   // 25.6 MB
    float* h2      = (float*)(ws + off); off += (size_t)NN * HH * 4;   // 25.6 MB
    float* dinv    = (float*)(ws + off); off += (size_t)NN * 4;
    int*   deg     = (int*)(ws + off);   off += (size_t)NN * 4;
    int*   row_ptr = (int*)(ws + off);   off += (size_t)(NN + 1) * 4 + 12;
    int*   srcs    = (int*)(ws + off);   off += (size_t)EE * 4;        // 3.2 MB
    float* gsum    = (float*)(ws + off); off += (size_t)GG * HH * 4;

    hipMemsetAsync(deg, 0, (size_t)NN * 4, stream);
    hipMemsetAsync(gsum, 0, (size_t)GG * HH * 4, stream);

    const int* src = ei;        // edge_index[0]
    const int* dst = ei + EE;   // edge_index[1]

    k_hist<<<EE / 256, 256, 0, stream>>>(dst, deg);
    k_scan<<<1, 1024, 0, stream>>>(deg, row_ptr, dinv);
    k_fill<<<EE / 256, 256, 0, stream>>>(src, dst, row_ptr, deg, srcs);
    k_gemm<<<(NN + 63) / 64, 256, 0, stream>>>(x, W, h);
    k_aggr<<<NN / 4, 256, 0, stream>>>(h, row_ptr, srcs, dinv, b, h2);
    k_pool<<<GG * 4, 128, 0, stream>>>(h2, batch, gsum);
    k_head<<<GG, 64, 0, stream>>>(gsum, batch, fc1_w, fc1_b, actor_w, actor_b,
                                  critic_w, critic_b, out);
}

// Round 2
// 321.318 us; speedup vs baseline: 1.5314x; 1.5314x over previous
//
#include <hip/hip_runtime.h>
#include <hip/hip_bf16.h>

#define NN 50000
#define EE 800000
#define FF 128
#define HH 128
#define HID2 64
#define TT 8
#define GG 64
#define NBLK ((NN + 255) / 256)   // 196

// ---------------- K1: in-degree histogram (dst side, excludes self-loop) ----
__global__ void k_hist(const int* __restrict__ dst, int* __restrict__ deg) {
    int e = blockIdx.x * 256 + threadIdx.x;
    if (e < EE) atomicAdd(&deg[dst[e]], 1);
}

// ---------------- K2a: per-block sums of deg -------------------------------
__global__ __launch_bounds__(256) void k_scan1(const int* __restrict__ deg,
                                               int* __restrict__ bsum) {
    __shared__ int red[256];
    int t = threadIdx.x;
    int i = blockIdx.x * 256 + t;
    red[t] = (i < NN) ? deg[i] : 0;
    __syncthreads();
    for (int off = 128; off >= 1; off >>= 1) {
        if (t < off) red[t] += red[t + off];
        __syncthreads();
    }
    if (t == 0) bsum[blockIdx.x] = red[0];
}

// ---------------- K2b: exclusive scan of 196 block sums (one tiny block) ---
__global__ __launch_bounds__(256) void k_scan2(int* __restrict__ bsum) {
    __shared__ int s[256];
    int t = threadIdx.x;
    int v = (t < NBLK) ? bsum[t] : 0;
    s[t] = v;
    __syncthreads();
    for (int off = 1; off < 256; off <<= 1) {
        int a = s[t];
        int b = (t >= off) ? s[t - off] : 0;
        __syncthreads();
        s[t] = a + b;
        __syncthreads();
    }
    if (t < NBLK) bsum[t] = (t == 0) ? 0 : s[t - 1];
}

// ---------------- K2c: in-block scan + offset -> row_ptr, dinv, zero deg ---
__global__ __launch_bounds__(256) void k_scan3(int* __restrict__ deg,
                                               const int* __restrict__ bsum,
                                               int* __restrict__ row_ptr,
                                               float* __restrict__ dinv) {
    __shared__ int s[256];
    int t = threadIdx.x;
    int i = blockIdx.x * 256 + t;
    int v = (i < NN) ? deg[i] : 0;
    s[t] = v;
    __syncthreads();
    for (int off = 1; off < 256; off <<= 1) {
        int a = s[t];
        int b = (t >= off) ? s[t - off] : 0;
        __syncthreads();
        s[t] = a + b;
        __syncthreads();
    }
    int excl = ((t == 0) ? 0 : s[t - 1]) + bsum[blockIdx.x];
    if (i < NN) {
        row_ptr[i] = excl;
        dinv[i] = rsqrtf((float)(v + 1));  // +1 self-loop
        deg[i] = 0;                        // reuse as fill cursor
        if (i == NN - 1) row_ptr[NN] = excl + v;
    }
}

// ---------------- K3: counting-sort fill of CSR col array ------------------
__global__ void k_fill(const int* __restrict__ src, const int* __restrict__ dst,
                       const int* __restrict__ row_ptr, int* __restrict__ cur,
                       int* __restrict__ srcs) {
    int e = blockIdx.x * 256 + threadIdx.x;
    if (e < EE) {
        int d = dst[e];
        int slot = row_ptr[d] + atomicAdd(&cur[d], 1);
        srcs[slot] = src[e];
    }
}

// ---------------- K4: h = x @ W  (fp32, LDS-tiled, 64x128 tile) ------------
__global__ __launch_bounds__(256) void k_gemm(const float* __restrict__ x,
                                              const float* __restrict__ W,
                                              float* __restrict__ h) {
    __shared__ float xs[64 * 36];   // 64 rows x 32 k, pad 36 (16B-aligned rows)
    __shared__ float ws[32 * 132];  // 32 k x 128 cols, pad 132
    int tid = threadIdx.x;
    int tx = tid & 15, ty = tid >> 4;
    int r0 = blockIdx.x * 64;
    float acc[4][8];
#pragma unroll
    for (int r = 0; r < 4; r++)
#pragma unroll
        for (int c = 0; c < 8; c++) acc[r][c] = 0.f;

    for (int k0 = 0; k0 < 128; k0 += 32) {
        {   // stage x tile: thread -> row=tid>>2, q=tid&3 (8 cols)
            int row = tid >> 2, q = tid & 3;
            int gr = r0 + row;
            float4 a0 = {0, 0, 0, 0}, a1 = {0, 0, 0, 0};
            if (gr < NN) {
                const float4* p = (const float4*)(x + (size_t)gr * 128 + k0 + q * 8);
                a0 = p[0]; a1 = p[1];
            }
            float* dp = &xs[row * 36 + q * 8];
            ((float4*)dp)[0] = a0; ((float4*)dp)[1] = a1;
        }
        {   // stage W tile: thread -> kr=tid>>3, q=tid&7 (16 cols)
            int kr = tid >> 3, q = tid & 7;
            const float4* p = (const float4*)(W + (size_t)(k0 + kr) * 128 + q * 16);
            float4 b0 = p[0], b1 = p[1], b2 = p[2], b3 = p[3];
            float* dp = &ws[kr * 132 + q * 16];
            ((float4*)dp)[0] = b0; ((float4*)dp)[1] = b1;
            ((float4*)dp)[2] = b2; ((float4*)dp)[3] = b3;
        }
        __syncthreads();
#pragma unroll
        for (int kk = 0; kk < 32; kk++) {
            float a[4];
#pragma unroll
            for (int r = 0; r < 4; r++) a[r] = xs[(ty * 4 + r) * 36 + kk];
            float4 b0 = *(const float4*)&ws[kk * 132 + tx * 8];
            float4 b1 = *(const float4*)&ws[kk * 132 + tx * 8 + 4];
            float bv[8] = {b0.x, b0.y, b0.z, b0.w, b1.x, b1.y, b1.z, b1.w};
#pragma unroll
            for (int r = 0; r < 4; r++)
#pragma unroll
                for (int c = 0; c < 8; c++)
                    acc[r][c] = fmaf(a[r], bv[c], acc[r][c]);
        }
        __syncthreads();
    }
#pragma unroll
    for (int r = 0; r < 4; r++) {
        int gr = r0 + ty * 4 + r;
        if (gr < NN) {
            float4 o0 = {acc[r][0], acc[r][1], acc[r][2], acc[r][3]};
            float4 o1 = {acc[r][4], acc[r][5], acc[r][6], acc[r][7]};
            float4* p = (float4*)(h + (size_t)gr * 128 + tx * 8);
            p[0] = o0; p[1] = o1;
        }
    }
}

// ---------------- K5: per-node gather aggregation + bias + relu ------------
__global__ __launch_bounds__(256) void k_aggr(const float* __restrict__ h,
                                              const int* __restrict__ row_ptr,
                                              const int* __restrict__ srcs,
                                              const float* __restrict__ dinv,
                                              const float* __restrict__ b,
                                              float* __restrict__ h2) {
    int wave = threadIdx.x >> 6;
    int lane = threadIdx.x & 63;
    int i = blockIdx.x * 4 + wave;  // grid sized so i < NN always
    float di = dinv[i];
    float2 v = ((const float2*)(h + (size_t)i * 128))[lane];
    float sw = di * di;  // self-loop weight
    float2 acc;
    acc.x = v.x * sw;
    acc.y = v.y * sw;
    int e0 = row_ptr[i], e1 = row_ptr[i + 1];
    for (int e = e0; e < e1; ++e) {
        int s = srcs[e];
        float w = dinv[s] * di;
        float2 hv = ((const float2*)(h + (size_t)s * 128))[lane];
        acc.x = fmaf(hv.x, w, acc.x);
        acc.y = fmaf(hv.y, w, acc.y);
    }
    float2 bb = ((const float2*)b)[lane];
    acc.x = fmaxf(acc.x + bb.x, 0.f);
    acc.y = fmaxf(acc.y + bb.y, 0.f);
    ((float2*)(h2 + (size_t)i * 128))[lane] = acc;
}

__device__ inline int lbound(const int* __restrict__ a, int n, int key) {
    int lo = 0, hi = n;
    while (lo < hi) {
        int mid = (lo + hi) >> 1;
        if (a[mid] < key) lo = mid + 1;
        else hi = mid;
    }
    return lo;
}

// ---------------- K6: group mean-pool partial sums (16 chunks/group) -------
__global__ __launch_bounds__(128) void k_pool(const float* __restrict__ h2,
                                              const int* __restrict__ batch,
                                              float* __restrict__ gsum) {
    int g = blockIdx.x >> 4, chunk = blockIdx.x & 15;
    int lo = lbound(batch, NN, g);
    int hi = lbound(batch, NN, g + 1);
    int cnt = hi - lo;
    int per = (cnt + 15) >> 4;
    int rs = lo + chunk * per;
    int re = rs + per;
    if (re > hi) re = hi;
    if (rs >= re) return;
    float s = 0.f;
    int f = threadIdx.x;
    for (int r = rs; r < re; ++r) s += h2[(size_t)r * 128 + f];
    atomicAdd(&gsum[g * 128 + f], s);
}

// ---------------- K7: head (fc1 + relu, actor softmax, critic) -------------
__global__ __launch_bounds__(64) void k_head(const float* __restrict__ gsum,
                                             const int* __restrict__ batch,
                                             const float* __restrict__ fc1_w,
                                             const float* __restrict__ fc1_b,
                                             const float* __restrict__ actor_w,
                                             const float* __restrict__ actor_b,
                                             const float* __restrict__ critic_w,
                                             const float* __restrict__ critic_b,
                                             float* __restrict__ out) {
    __shared__ float gs[128];
    __shared__ float zs[64];
    __shared__ float ls[8], es[8];
    int g = blockIdx.x, t = threadIdx.x;
    int lo = lbound(batch, NN, g), hi = lbound(batch, NN, g + 1);
    float invc = 1.f / fmaxf((float)(hi - lo), 1.f);
    gs[t] = gsum[g * 128 + t] * invc;
    gs[t + 64] = gsum[g * 128 + 64 + t] * invc;
    __syncthreads();
    float z = fc1_b[t];
    for (int k = 0; k < 128; k++) z = fmaf(gs[k], fc1_w[k * 64 + t], z);
    zs[t] = fmaxf(z, 0.f);
    __syncthreads();
    if (t < 8) {
        float l = actor_b[t];
        for (int k = 0; k < 64; k++) l = fmaf(zs[k], actor_w[k * 8 + t], l);
        ls[t] = l;
    }
    __syncthreads();
    if (t < 8) {
        float m = ls[0];
#pragma unroll
        for (int j = 1; j < 8; j++) m = fmaxf(m, ls[j]);
        es[t] = expf(ls[t] - m);
    }
    __syncthreads();
    if (t < 8) {
        float ssum = 0.f;
#pragma unroll
        for (int j = 0; j < 8; j++) ssum += es[j];
        out[g * 8 + t] = es[t] / ssum;
    }
    if (t == 32) {
        float v = critic_b[0];
        for (int k = 0; k < 64; k++) v = fmaf(zs[k], critic_w[k], v);
        out[GG * TT + g] = v;
    }
}

extern "C" void kernel_launch(void* const* d_in, const int* in_sizes, int n_in,
                              void* d_out, int out_size, void* d_ws, size_t ws_size,
                              hipStream_t stream) {
    const float* x        = (const float*)d_in[0];
    const int*   ei       = (const int*)d_in[1];
    const int*   batch    = (const int*)d_in[2];
    const float* W        = (const float*)d_in[3];
    const float* b        = (const float*)d_in[4];
    const float* fc1_w    = (const float*)d_in[5];
    const float* fc1_b    = (const float*)d_in[6];
    const float* actor_w  = (const float*)d_in[7];
    const float* actor_b  = (const float*)d_in[8];
    const float* critic_w = (const float*)d_in[9];
    const float* critic_b = (const float*)d_in[10];
    float* out = (float*)d_out;

    char* ws = (char*)d_ws;
    size_t off = 0;
    float* h       = (float*)(ws + off); off += (size_t)NN * HH * 4;   // 25.6 MB
    float* h2      = (float*)(ws + off); off += (size_t)NN * HH * 4;   // 25.6 MB
    float* dinv    = (float*)(ws + off); off += (size_t)NN * 4;
    int*   deg     = (int*)(ws + off);   off += (size_t)NN * 4;
    int*   row_ptr = (int*)(ws + off);   off += (size_t)(NN + 1) * 4 + 12;
    int*   srcs    = (int*)(ws + off);   off += (size_t)EE * 4;        // 3.2 MB
    float* gsum    = (float*)(ws + off); off += (size_t)GG * HH * 4;
    int*   bsum    = (int*)(ws + off);   off += (size_t)256 * 4;

    hipMemsetAsync(deg, 0, (size_t)NN * 4, stream);
    hipMemsetAsync(gsum, 0, (size_t)GG * HH * 4, stream);

    const int* src = ei;        // edge_index[0]
    const int* dst = ei + EE;   // edge_index[1]

    k_hist<<<EE / 256, 256, 0, stream>>>(dst, deg);
    k_scan1<<<NBLK, 256, 0, stream>>>(deg, bsum);
    k_scan2<<<1, 256, 0, stream>>>(bsum);
    k_scan3<<<NBLK, 256, 0, stream>>>(deg, bsum, row_ptr, dinv);
    k_fill<<<EE / 256, 256, 0, stream>>>(src, dst, row_ptr, deg, srcs);
    k_gemm<<<(NN + 63) / 64, 256, 0, stream>>>(x, W, h);
    k_aggr<<<NN / 4, 256, 0, stream>>>(h, row_ptr, srcs, dinv, b, h2);
    k_pool<<<GG * 16, 128, 0, stream>>>(h2, batch, gsum);
    k_head<<<GG, 64, 0, stream>>>(gsum, batch, fc1_w, fc1_b, actor_w, actor_b,
                                  critic_w, critic_b, out);
}